// Round 6
// baseline (139.145 us; speedup 1.0000x reference)
//
#include <hip/hip_runtime.h>
#include <hip/hip_fp16.h>

#define N_DET 128
#define N_T   2048
#define NPIX  65536   // 256*256
#define NBATCH 4
#define G 4                   // det rows per block (4 x 16 KB = 64 KB LDS)
#define NGRP (N_DET / G)      // 32 det-group blocks per pixel
#define NTILE 16              // pixel tiles
#define TPX (NPIX / NTILE)    // 4096 px per tile
#define THREADS 512
#define IPT (TPX / THREADS)   // 8 pixel-iters per thread

typedef float f4_t __attribute__((ext_vector_type(4)));

// Kernel 1: transpose+pack sino (B, N_DET, N_T) fp32 -> ws (N_DET, N_T) of
// 8-byte records { s_t[b0..b3] } as 4 fp16. ws = 2 MB (L2-resident per XCD).
// Also zeroes out[] for kernel 2's atomic accumulation.
__global__ __launch_bounds__(256) void sino_pack_kernel(
    const float* __restrict__ sino, float2* __restrict__ ws,
    float* __restrict__ out) {
  const int idx = blockIdx.x * blockDim.x + threadIdx.x;  // idx = d*N_T + t
  const __half2 lo = __floats2half2_rn(
      __builtin_nontemporal_load(sino + 0 * N_DET * N_T + idx),
      __builtin_nontemporal_load(sino + 1 * N_DET * N_T + idx));
  const __half2 hi = __floats2half2_rn(
      __builtin_nontemporal_load(sino + 2 * N_DET * N_T + idx),
      __builtin_nontemporal_load(sino + 3 * N_DET * N_T + idx));
  union { struct { __half2 a, b; } h; float2 f; } u;
  u.h.a = lo;
  u.h.b = hi;
  ws[idx] = u.f;
  out[idx] = 0.0f;  // exact cover: 128*2048 == 4*65536
}

// Kernel 2: barrier-free steady-state LDS-gather.
// Diagnosis r0-r5: every variant sat at 42-48 us because lut loads come in a
// burst at block start, a barrier drains vmcnt, then compute issues NO global
// loads -> HBM duty cycle ~25% -> 1.5-2 TB/s (measured, every round).
// Little's law: full BW needs only ~9 KB/CU in flight CONTINUOUSLY.
// Fix: stage LDS once; then an 8-iter loop {prefetch next lut (2 b128) ->
// compute 4 det-units -> 4 atomicAdds} with NO barrier (LDS is read-only
// after the stage). Steady-state in-flight = 16 waves x 2 KB = 32 KB/CU.
//  - grid = 512 blocks exactly = 2 resident/CU for the WHOLE kernel: the 32
//    det-group blocks of a tile are truly concurrent on one XCD (r5's merge
//    failed only because same-tile blocks ran in different dispatch rounds).
//  - XCD swizzle: T = ((b>>8)<<3)|(b&7), g = (b>>3)&31 -> all g of tile T on
//    XCD T&7; also puts the g/g^1 blocks sharing each 64 B lut line on the
//    same L2 (each block uses 32 B of the line).
//  - launch_bounds(512,4): VGPR cap 128 (r1/r4 lesson: tighter caps strangle
//    the allocator and serialize load chains).
__global__ __launch_bounds__(512, 4) void das_lds_kernel(
    const float* __restrict__ lut, const float2* __restrict__ ws,
    float* __restrict__ out) {
  __shared__ __align__(16) float2 sbuf[G][N_T];  // 64 KB

  const int b = blockIdx.x;
  const int T = ((b >> 8) << 3) | (b & 7);  // tile 0..15
  const int g = (b >> 3) & 31;              // det-group 0..31
  const int tid = threadIdx.x;

  // Per-iter lut pointer: px(i) = T*TPX + i*THREADS + tid; 32 B per px
  // (this group's 4 dets x (tof,alpha)).
  const char* lb = reinterpret_cast<const char*>(lut) +
                   ((size_t)(T * TPX + tid) * (N_DET * 8)) + (size_t)g * (G * 8);
  // iter stride in bytes: THREADS px * 1024 B/px
  const size_t istride = (size_t)THREADS * (N_DET * 8);

  // Prologue: issue iter-0 lut loads first (hide HBM latency under staging).
  f4_t lc0 = reinterpret_cast<const f4_t*>(lb)[0];
  f4_t lc1 = reinterpret_cast<const f4_t*>(lb)[1];

  // Stage 4 det rows (64 KB) from L2-resident ws via async global_load_lds.
  // dst = wave-uniform base + lane*16 (HW requirement) -- linear mapping.
  {
    const char* src = reinterpret_cast<const char*>(ws) + (size_t)g * 65536;
    char* dstb = reinterpret_cast<char*>(&sbuf[0][0]);
#pragma unroll
    for (int r = 0; r < 8; ++r) {
      __builtin_amdgcn_global_load_lds(
          (const __attribute__((address_space(1))) void*)(src + r * 8192 +
                                                          tid * 16),
          (__attribute__((address_space(3))) void*)(dstb + r * 8192 + tid * 16),
          16, 0, 0);
    }
  }

  // Apodization for this group's 4 dets (wave-uniform).
  float apd[G];
#pragma unroll
  for (int dd = 0; dd < G; ++dd)
    apd[dd] = 0.5f - 0.5f * cosf(6.28318530717958647692f *
                                 ((float)(g * G + dd) / 127.0f));

  __syncthreads();  // the ONLY barrier: stage + iter-0 lut drained

  const float nrm = 1.0f / 63.5f;  // sum(apod) == 63.5 analytically

#pragma unroll
  for (int i = 0; i < IPT; ++i) {
    // Prefetch next iter's lut: keeps global loads in flight through compute.
    f4_t ln0, ln1;
    if (i + 1 < IPT) {
      const f4_t* lp = reinterpret_cast<const f4_t*>(lb + (size_t)(i + 1) * istride);
      ln0 = lp[0];
      ln1 = lp[1];
    }

    float ax = 0.f, ay = 0.f, az = 0.f, aw = 0.f;
#pragma unroll
    for (int dd = 0; dd < G; ++dd) {
      const f4_t& lv = (dd < 2) ? lc0 : lc1;
      const float tof = (dd & 1) ? lv.z : lv.x;
      const float al  = (dd & 1) ? lv.w : lv.y;
      const float kf = floorf(tof);
      const bool valid = (kf >= 0.0f) && (kf < (float)(N_T - 1));
      const int k0 = (int)fminf(fmaxf(kf, 0.0f), (float)(N_T - 2));
      const float w = valid ? apd[dd] : 0.0f;

      const float2 r0 = sbuf[dd][k0];      // ds_read_b64: tap t
      const float2 r1 = sbuf[dd][k0 + 1];  // ds_read_b64: tap t+1
      const __half2* h0 = reinterpret_cast<const __half2*>(&r0);
      const __half2* h1 = reinterpret_cast<const __half2*>(&r1);
      const float2 s0a = __half22float2(h0[0]);  // t:   b0,b1
      const float2 s0b = __half22float2(h0[1]);  // t:   b2,b3
      const float2 s1a = __half22float2(h1[0]);  // t+1: b0,b1
      const float2 s1b = __half22float2(h1[1]);  // t+1: b2,b3

      ax += w * (s0a.x + al * (s1a.x - s0a.x));
      ay += w * (s0a.y + al * (s1a.y - s0a.y));
      az += w * (s0b.x + al * (s1b.x - s0b.x));
      aw += w * (s0b.y + al * (s1b.y - s0b.y));
    }

    const int P = T * TPX + i * THREADS + tid;
    atomicAdd(out + 0 * NPIX + P, ax * nrm);
    atomicAdd(out + 1 * NPIX + P, ay * nrm);
    atomicAdd(out + 2 * NPIX + P, az * nrm);
    atomicAdd(out + 3 * NPIX + P, aw * nrm);

    lc0 = ln0;
    lc1 = ln1;
  }
}

// Fallback (no workspace): direct fp32 gather from original layout.
__global__ __launch_bounds__(256) void das_fallback_kernel(
    const float* __restrict__ lut, const float* __restrict__ S,
    float* __restrict__ out) {
  const int lane = threadIdx.x & 63;
  const int p = blockIdx.x * 4 + (threadIdx.x >> 6);

  const float4 lv =
      reinterpret_cast<const float4*>(lut + (size_t)p * 2 * N_DET)[lane];

  float acc0 = 0.f, acc1 = 0.f, acc2 = 0.f, acc3 = 0.f;
  float wsum = 0.f;

#pragma unroll
  for (int j = 0; j < 2; ++j) {
    const int d = 2 * lane + j;
    const float tof = j ? lv.z : lv.x;
    const float a   = j ? lv.w : lv.y;
    const float kf = floorf(tof);
    const bool valid = (kf >= 0.0f) && (kf < (float)(N_T - 1));
    const float kcl = fminf(fmaxf(kf, 0.0f), (float)(N_T - 2));
    const int k0 = (int)kcl;
    const float apd =
        0.5f - 0.5f * cosf(6.28318530717958647692f *
                           (1.0f / (float)(N_DET - 1)) * (float)d);
    wsum += apd;
    const float w = valid ? apd : 0.0f;
    const float om = 1.0f - a;
    const float* row = S + (size_t)d * N_T + k0;
    acc0 += w * (om * row[0 * N_DET * N_T] + a * row[0 * N_DET * N_T + 1]);
    acc1 += w * (om * row[1 * N_DET * N_T] + a * row[1 * N_DET * N_T + 1]);
    acc2 += w * (om * row[2 * N_DET * N_T] + a * row[2 * N_DET * N_T + 1]);
    acc3 += w * (om * row[3 * N_DET * N_T] + a * row[3 * N_DET * N_T + 1]);
  }

#pragma unroll
  for (int off = 32; off > 0; off >>= 1) {
    acc0 += __shfl_xor(acc0, off);
    acc1 += __shfl_xor(acc1, off);
    acc2 += __shfl_xor(acc2, off);
    acc3 += __shfl_xor(acc3, off);
    wsum += __shfl_xor(wsum, off);
  }

  if (lane == 0) {
    const float inv = 1.0f / fmaxf(wsum, 1.17549435e-38f);
    out[0 * NPIX + p] = acc0 * inv;
    out[1 * NPIX + p] = acc1 * inv;
    out[2 * NPIX + p] = acc2 * inv;
    out[3 * NPIX + p] = acc3 * inv;
  }
}

extern "C" void kernel_launch(void* const* d_in, const int* in_sizes, int n_in,
                              void* d_out, int out_size, void* d_ws, size_t ws_size,
                              hipStream_t stream) {
  const float* sino = (const float*)d_in[0];  // (B,1,N_DET,N_T) fp32
  const float* lut  = (const float*)d_in[1];  // (NY,NX,N_DET,2) fp32
  float* out = (float*)d_out;                 // (B,1,NY,NX) fp32

  const size_t need = (size_t)N_DET * N_T * 8;  // 2 MB packed ws
  if (ws_size >= need) {
    float2* ws = (float2*)d_ws;
    sino_pack_kernel<<<(N_DET * N_T) / 256, 256, 0, stream>>>(sino, ws, out);
    das_lds_kernel<<<NGRP * NTILE, THREADS, 0, stream>>>(lut, ws, out);
  } else {
    das_fallback_kernel<<<NPIX / 4, 256, 0, stream>>>(lut, sino, out);
  }
}

// Round 7
// 129.427 us; speedup vs baseline: 1.0751x; 1.0751x over previous
//
#include <hip/hip_runtime.h>
#include <hip/hip_fp16.h>

#define N_DET 128
#define N_T   2048
#define NPIX  65536   // 256*256
#define NBATCH 4
#define G 4                   // det rows per block (4 x 16 KB = 64 KB LDS)
#define NGRP (N_DET / G)      // 32 det-group blocks per pixel
#define THREADS 512
#define PXT 8                 // pixels per thread (16 b128 lut loads in flight)
#define TPX (THREADS * PXT)   // 4096 px per tile
#define NTILE (NPIX / TPX)    // 16

typedef float f4_t __attribute__((ext_vector_type(4)));

// Kernel 1: transpose+pack sino (B, N_DET, N_T) fp32 -> ws (N_DET, N_T) of
// 8-byte records { s_t[b0..b3] } as 4 fp16. ws = 2 MB (L2-resident per XCD).
// Also zeroes out[] for kernel 2's atomic accumulation.
__global__ __launch_bounds__(256) void sino_pack_kernel(
    const float* __restrict__ sino, float2* __restrict__ ws,
    float* __restrict__ out) {
  const int idx = blockIdx.x * blockDim.x + threadIdx.x;  // idx = d*N_T + t
  const __half2 lo = __floats2half2_rn(
      __builtin_nontemporal_load(sino + 0 * N_DET * N_T + idx),
      __builtin_nontemporal_load(sino + 1 * N_DET * N_T + idx));
  const __half2 hi = __floats2half2_rn(
      __builtin_nontemporal_load(sino + 2 * N_DET * N_T + idx),
      __builtin_nontemporal_load(sino + 3 * N_DET * N_T + idx));
  union { struct { __half2 a, b; } h; float2 f; } u;
  u.h.a = lo;
  u.h.b = hi;
  ws[idx] = u.f;
  out[idx] = 0.0f;  // exact cover: 128*2048 == 4*65536
}

// Kernel 2: burst LDS-gather, max (waves/CU x in-flight-loads/wave).
// r0-r6 regression: das time tracks in-flight lut loads per thread at the
// wait point (16->42us, 8->43us, 2->61us), NOT temporal duty cycle. HW cap:
// 4 waves/SIMD at <=128 VGPR (pool 2048/SIMD). So: 16 waves/CU and 16 b128
// in flight per thread simultaneously.
//  - G=4 -> 64 KB LDS, 512 threads, 2 blocks/CU, grid=512 = single resident
//    round: ALL blocks of a tile concurrent (r5/r6: multi-round scheduling
//    defeated the atomic L2-merge; WRITE_SIZE stayed 32 MB).
//  - swizzle: XCD = b&7; tile T = (b&7)|(((b>>3)&1)<<3); g = b>>4.
//    All 32 g-blocks of tile T sit on XCD T&7, one per CU, concurrently ->
//    same-line atomicAdds merge in that XCD's L2. Each CU pairs tile x and
//    tile x+8 at the SAME g -> staging reads shared in L2.
//  - launch_bounds(512,4): VGPR cap 128 (r1/r4/r6 lesson: lower caps
//    serialize the load burst; expect ~100 VGPR).
__global__ __launch_bounds__(512, 4) void das_lds_kernel(
    const float* __restrict__ lut, const float2* __restrict__ ws,
    float* __restrict__ out) {
  __shared__ __align__(16) float2 sbuf[G][N_T];  // 64 KB

  const int b = blockIdx.x;
  const int T = (b & 7) | (((b >> 3) & 1) << 3);  // tile 0..15
  const int g = b >> 4;                           // det-group 0..31
  const int tid = threadIdx.x;

  // 1) lut burst FIRST: 8 px x 32 B = 16 independent b128 in flight.
  //    (HBM ~900 cyc latency hides under the stage + apod + barrier below.)
  f4_t l[PXT][2];
  const char* lb = reinterpret_cast<const char*>(lut) + (size_t)g * (G * 8);
#pragma unroll
  for (int i = 0; i < PXT; ++i) {
    const size_t P = (size_t)T * TPX + i * THREADS + tid;
    const f4_t* lp = reinterpret_cast<const f4_t*>(lb + P * (N_DET * 8));
    l[i][0] = lp[0];
    l[i][1] = lp[1];
  }

  // 2) Stage 4 det rows (64 KB) from L2-resident ws via async global_load_lds.
  //    dst = wave-uniform base + lane*16 (HW requirement) -- linear mapping.
  {
    const char* src = reinterpret_cast<const char*>(ws) + (size_t)g * 65536;
    char* dstb = reinterpret_cast<char*>(&sbuf[0][0]);
#pragma unroll
    for (int r = 0; r < 8; ++r) {
      __builtin_amdgcn_global_load_lds(
          (const __attribute__((address_space(1))) void*)(src + r * 8192 +
                                                          tid * 16),
          (__attribute__((address_space(3))) void*)(dstb + r * 8192 + tid * 16),
          16, 0, 0);
    }
  }

  // Apodization for this group's 4 dets (wave-uniform).
  float apd[G];
#pragma unroll
  for (int dd = 0; dd < G; ++dd)
    apd[dd] = 0.5f - 0.5f * cosf(6.28318530717958647692f *
                                 ((float)(g * G + dd) / 127.0f));

  __syncthreads();  // single barrier: stage + lut burst drained

  const float nrm = 1.0f / 63.5f;  // sum(apod) == 63.5 analytically

#pragma unroll
  for (int i = 0; i < PXT; ++i) {
    float ax = 0.f, ay = 0.f, az = 0.f, aw = 0.f;
#pragma unroll
    for (int dd = 0; dd < G; ++dd) {
      const f4_t& lv = l[i][dd >> 1];
      const float tof = (dd & 1) ? lv.z : lv.x;
      const float al  = (dd & 1) ? lv.w : lv.y;
      const float kf = floorf(tof);
      const bool valid = (kf >= 0.0f) && (kf < (float)(N_T - 1));
      const int k0 = (int)fminf(fmaxf(kf, 0.0f), (float)(N_T - 2));
      const float w = valid ? apd[dd] : 0.0f;

      const float2 r0 = sbuf[dd][k0];      // ds_read2_b64: taps t, t+1
      const float2 r1 = sbuf[dd][k0 + 1];
      const __half2* h0 = reinterpret_cast<const __half2*>(&r0);
      const __half2* h1 = reinterpret_cast<const __half2*>(&r1);
      const float2 s0a = __half22float2(h0[0]);  // t:   b0,b1
      const float2 s0b = __half22float2(h0[1]);  // t:   b2,b3
      const float2 s1a = __half22float2(h1[0]);  // t+1: b0,b1
      const float2 s1b = __half22float2(h1[1]);  // t+1: b2,b3

      ax += w * (s0a.x + al * (s1a.x - s0a.x));
      ay += w * (s0a.y + al * (s1a.y - s0a.y));
      az += w * (s0b.x + al * (s1b.x - s0b.x));
      aw += w * (s0b.y + al * (s1b.y - s0b.y));
    }

    const int P = T * TPX + i * THREADS + tid;
    atomicAdd(out + 0 * NPIX + P, ax * nrm);
    atomicAdd(out + 1 * NPIX + P, ay * nrm);
    atomicAdd(out + 2 * NPIX + P, az * nrm);
    atomicAdd(out + 3 * NPIX + P, aw * nrm);
  }
}

// Fallback (no workspace): direct fp32 gather from original layout.
__global__ __launch_bounds__(256) void das_fallback_kernel(
    const float* __restrict__ lut, const float* __restrict__ S,
    float* __restrict__ out) {
  const int lane = threadIdx.x & 63;
  const int p = blockIdx.x * 4 + (threadIdx.x >> 6);

  const float4 lv =
      reinterpret_cast<const float4*>(lut + (size_t)p * 2 * N_DET)[lane];

  float acc0 = 0.f, acc1 = 0.f, acc2 = 0.f, acc3 = 0.f;
  float wsum = 0.f;

#pragma unroll
  for (int j = 0; j < 2; ++j) {
    const int d = 2 * lane + j;
    const float tof = j ? lv.z : lv.x;
    const float a   = j ? lv.w : lv.y;
    const float kf = floorf(tof);
    const bool valid = (kf >= 0.0f) && (kf < (float)(N_T - 1));
    const float kcl = fminf(fmaxf(kf, 0.0f), (float)(N_T - 2));
    const int k0 = (int)kcl;
    const float apd =
        0.5f - 0.5f * cosf(6.28318530717958647692f *
                           (1.0f / (float)(N_DET - 1)) * (float)d);
    wsum += apd;
    const float w = valid ? apd : 0.0f;
    const float om = 1.0f - a;
    const float* row = S + (size_t)d * N_T + k0;
    acc0 += w * (om * row[0 * N_DET * N_T] + a * row[0 * N_DET * N_T + 1]);
    acc1 += w * (om * row[1 * N_DET * N_T] + a * row[1 * N_DET * N_T + 1]);
    acc2 += w * (om * row[2 * N_DET * N_T] + a * row[2 * N_DET * N_T + 1]);
    acc3 += w * (om * row[3 * N_DET * N_T] + a * row[3 * N_DET * N_T + 1]);
  }

#pragma unroll
  for (int off = 32; off > 0; off >>= 1) {
    acc0 += __shfl_xor(acc0, off);
    acc1 += __shfl_xor(acc1, off);
    acc2 += __shfl_xor(acc2, off);
    acc3 += __shfl_xor(acc3, off);
    wsum += __shfl_xor(wsum, off);
  }

  if (lane == 0) {
    const float inv = 1.0f / fmaxf(wsum, 1.17549435e-38f);
    out[0 * NPIX + p] = acc0 * inv;
    out[1 * NPIX + p] = acc1 * inv;
    out[2 * NPIX + p] = acc2 * inv;
    out[3 * NPIX + p] = acc3 * inv;
  }
}

extern "C" void kernel_launch(void* const* d_in, const int* in_sizes, int n_in,
                              void* d_out, int out_size, void* d_ws, size_t ws_size,
                              hipStream_t stream) {
  const float* sino = (const float*)d_in[0];  // (B,1,N_DET,N_T) fp32
  const float* lut  = (const float*)d_in[1];  // (NY,NX,N_DET,2) fp32
  float* out = (float*)d_out;                 // (B,1,NY,NX) fp32

  const size_t need = (size_t)N_DET * N_T * 8;  // 2 MB packed ws
  if (ws_size >= need) {
    float2* ws = (float2*)d_ws;
    sino_pack_kernel<<<(N_DET * N_T) / 256, 256, 0, stream>>>(sino, ws, out);
    das_lds_kernel<<<NTILE * NGRP, THREADS, 0, stream>>>(lut, ws, out);
  } else {
    das_fallback_kernel<<<NPIX / 4, 256, 0, stream>>>(lut, sino, out);
  }
}